// Round 6
// baseline (1412.937 us; speedup 1.0000x reference)
//
#include <hip/hip_runtime.h>
#include <hip/hip_bf16.h>

#define NIN 32
#define NHID 128
#define NOUT 16
#define NIN1 160   // NIN+NHID
#define SEQT 512
#define NB 256
#define NSEG 8
#define SEGI 20    // i's per segment (8 segments x 128 o = 1024 threads)

#if defined(__has_builtin)
#if __has_builtin(__builtin_amdgcn_fdot2_f32_bf16)
#define HAVE_DOT2BF 1
#endif
#endif
#ifndef HAVE_DOT2BF
#define HAVE_DOT2BF 0
#endif

// manual RNE f32->bf16 (inputs are finite/sane here)
__device__ __forceinline__ unsigned int f2bfbits(float f) {
    unsigned int u = __float_as_uint(f);
    return (u + 0x7fffu + ((u >> 16) & 1u)) >> 16;
}
__device__ __forceinline__ unsigned int packbf(float lo, float hi) {
    return f2bfbits(lo) | (f2bfbits(hi) << 16);
}

#if HAVE_DOT2BF
typedef __bf16 bf16x2 __attribute__((ext_vector_type(2)));
__device__ __forceinline__ float dot2w(unsigned int a, unsigned int b, float c) {
    return __builtin_amdgcn_fdot2_f32_bf16(__builtin_bit_cast(bf16x2, a),
                                           __builtin_bit_cast(bf16x2, b), c, false);
}
#else
__device__ __forceinline__ float dot2w(unsigned int a, unsigned int b, float c) {
    float alo = __uint_as_float(a << 16), ahi = __uint_as_float(a & 0xffff0000u);
    float blo = __uint_as_float(b << 16), bhi = __uint_as_float(b & 0xffff0000u);
    return __builtin_fmaf(ahi, bhi, __builtin_fmaf(alo, blo, c));
}
#endif

// Knots: t_m = -8.8 + 1.6*m (G=5, K=3, range [-4,4]); verified rounds 3-5 PASS.
__device__ __forceinline__ void spline_feat(float c, float* out4, int* jst) {
    const float t0 = -8.8f, hh = 1.6f;
    int m0 = (int)floorf((c - t0) / hh);
    bool valid = (m0 >= 0) && (m0 <= 10);
    float v0 = 1.f, v1 = 0.f, v2 = 0.f, v3 = 0.f;
    #pragma unroll
    for (int d = 1; d <= 3; ++d) {
        float inv = 1.f / (d * hh);
        float nv[4];
        float pv[4] = {v0, v1, v2, v3};
        #pragma unroll
        for (int r = 3; r >= 0; --r) {
            if (r > d) { nv[r] = 0.f; continue; }
            int m = m0 - d + r;
            float tm = t0 + hh * (float)m;
            float left  = (r >= 1) ? pv[r-1] : 0.f;
            float right = (r <= d-1) ? pv[r] : 0.f;
            nv[r] = ((c - tm) * left + (tm + hh * (float)(d+1) - c) * right) * inv;
        }
        v0 = nv[0]; v1 = nv[1]; v2 = nv[2]; v3 = nv[3];
    }
    float v[4] = {v0, v1, v2, v3};
    int jb = m0 - 3;
    int js = jb < 0 ? 0 : (jb > 4 ? 4 : jb);
    int sh = js - jb;
    #pragma unroll
    for (int r = 0; r < 4; ++r) {
        int rs = r + sh;
        out4[r] = (valid && rs >= 0 && rs <= 3) ? v[rs] : 0.f;
    }
    *jst = js;
}

// fast silu: 1-ulp rcp (features are bf16-rounded anyway)
__device__ __forceinline__ float fsilu(float c) {
    return c * __builtin_amdgcn_rcpf(1.f + __expf(-c));
}

// 10 weight pairs per thread (20 i's), named scalars.
// Per thread: 10*(4+4+1) = 90 VGPRs of weights -> fits the 128-VGPR budget
// that a 1024-thread block gets (4 waves/EU minimum). [r4/r5: 512-thr blocks
// were hard-capped at 128 VGPR and spilled a 180-reg live set to scratch]
#define R10(X) X(0) X(1) X(2) X(3) X(4) X(5) X(6) X(7) X(8) X(9)

__attribute__((amdgpu_waves_per_eu(4, 4)))
__global__ void __launch_bounds__(1024)
kan_seq(const float* __restrict__ x,
        const float* __restrict__ coef1,
        const float* __restrict__ sb1,
        const float* __restrict__ sp1,
        const float* __restrict__ coef2,
        const float* __restrict__ sb2,
        const float* __restrict__ sp2,
        float* __restrict__ out)
{
    __shared__ __align__(16) unsigned int Fb[NIN1][4];  // 8 bf16 basis per record
    __shared__ float Fsil[NIN1];                        // silu per record (f32)
    __shared__ float red[NSEG][NHID];                   // per-seg partial sums
    __shared__ float Hf[NHID][9];                       // epilogue h-features

    const int tid  = threadIdx.x;
    const int b    = blockIdx.x;           // one batch row per block
    const int o    = tid & 127;
    const int seg  = tid >> 7;             // 0..7
    const int i0   = seg * SEGI;
    const int lane = tid & 63;

    // ---- one-time: layer-1 weights -> registers, bf16-packed, sp1 folded ----
#define DECLP(p) uint4 wA##p, wB##p; unsigned int sbp##p;
    R10(DECLP)
#undef DECLP

#define INITP(p) { \
    const int iA = i0 + 2 * (p), iB = i0 + 2 * (p) + 1; \
    const float4* ca = (const float4*)(coef1 + (size_t)(iA * NHID + o) * 8); \
    const float4* cb = (const float4*)(coef1 + (size_t)(iB * NHID + o) * 8); \
    float spA = sp1[iA * NHID + o], spB = sp1[iB * NHID + o]; \
    float4 a0 = ca[0], a1 = ca[1], b0v = cb[0], b1v = cb[1]; \
    wA##p = make_uint4(packbf(spA * a0.x, spA * a0.y), packbf(spA * a0.z, spA * a0.w), \
                       packbf(spA * a1.x, spA * a1.y), packbf(spA * a1.z, spA * a1.w)); \
    wB##p = make_uint4(packbf(spB * b0v.x, spB * b0v.y), packbf(spB * b0v.z, spB * b0v.w), \
                       packbf(spB * b1v.x, spB * b1v.y), packbf(spB * b1v.z, spB * b1v.w)); \
    sbp##p = packbf(sb1[iA * NHID + o], sb1[iB * NHID + o]); }
    R10(INITP)
#undef INITP

    ((float*)red)[tid] = 0.f;   // h0 = 0 (red is exactly 1024 floats)
    float xv = (tid < NIN) ? x[(size_t)b * SEQT * NIN + tid] : 0.f;
    __syncthreads();

    for (int t = 0; t < SEQT; ++t) {
        // ---- phase 1: features (silu + sparse basis) for all 160 inputs ----
        if (tid < NIN1) {
            float c;
            if (tid < NIN) c = xv;
            else {
                int hi = tid - NIN;
                float s0 = red[0][hi] + red[1][hi], s1 = red[2][hi] + red[3][hi];
                float s2 = red[4][hi] + red[5][hi], s3 = red[6][hi] + red[7][hi];
                c = (s0 + s1) + (s2 + s3);
            }
            float sil = fsilu(c);
            float b4[4]; int js;
            spline_feat(c, b4, &js);
            float e[8];
            #pragma unroll
            for (int k = 0; k < 8; ++k) {
                int d = k - js;
                e[k] = (d >= 0 && d < 4) ? b4[d] : 0.f;
            }
            uint4 pk;
            pk.x = packbf(e[0], e[1]); pk.y = packbf(e[2], e[3]);
            pk.z = packbf(e[4], e[5]); pk.w = packbf(e[6], e[7]);
            *(uint4*)&Fb[tid][0] = pk;
            Fsil[tid] = sil;
        }
        if (tid < NIN) {   // prefetch next timestep's x
            int tn = (t + 1 < SEQT) ? (t + 1) : t;
            xv = x[((size_t)b * SEQT + tn) * NIN + tid];
        }
        __syncthreads();

        // ---- phase 2: register weights x LDS-broadcast features ----
        float vsil = Fsil[i0 + (lane < SEGI ? lane : 0)];  // lane-parallel silu preload
        float ac0 = 0.f, ac1 = 0.f, ac2 = 0.f, ac3 = 0.f;
#define DOTP(p) { \
        float sb_lo = __uint_as_float(sbp##p << 16); \
        float sb_hi = __uint_as_float(sbp##p & 0xffff0000u); \
        float slA = __int_as_float(__builtin_amdgcn_readlane(__float_as_int(vsil), 2 * (p))); \
        float slB = __int_as_float(__builtin_amdgcn_readlane(__float_as_int(vsil), 2 * (p) + 1)); \
        uint4 bA = *(const uint4*)&Fb[i0 + 2 * (p)][0]; \
        uint4 bB = *(const uint4*)&Fb[i0 + 2 * (p) + 1][0]; \
        ac0 = __builtin_fmaf(slA, sb_lo, ac0); \
        ac0 = dot2w(bA.x, wA##p.x, ac0); ac1 = dot2w(bA.y, wA##p.y, ac1); \
        ac2 = dot2w(bA.z, wA##p.z, ac2); ac3 = dot2w(bA.w, wA##p.w, ac3); \
        ac1 = __builtin_fmaf(slB, sb_hi, ac1); \
        ac0 = dot2w(bB.x, wB##p.x, ac0); ac1 = dot2w(bB.y, wB##p.y, ac1); \
        ac2 = dot2w(bB.z, wB##p.z, ac2); ac3 = dot2w(bB.w, wB##p.w, ac3); }
        R10(DOTP)
#undef DOTP
        red[seg][o] = (ac0 + ac1) + (ac2 + ac3);
        __syncthreads();
    }

    // ---- layer 2 on final h only (fp32; verified rounds 3-5) ----
    if (tid < NHID) {
        float s0 = red[0][tid] + red[1][tid], s1 = red[2][tid] + red[3][tid];
        float s2 = red[4][tid] + red[5][tid], s3 = red[6][tid] + red[7][tid];
        float c = (s0 + s1) + (s2 + s3);
        float sil = fsilu(c);
        float b4[4]; int js;
        spline_feat(c, b4, &js);
        #pragma unroll
        for (int k = 0; k < 8; ++k) {
            int d = k - js;
            Hf[tid][k] = (d >= 0 && d < 4) ? b4[d] : 0.f;
        }
        Hf[tid][8] = sil;
    }
    __syncthreads();
    if (tid < 128) {
        int o2 = tid & 15, isg = tid >> 4;     // 8 i-groups of 16
        float acc = 0.f;
        for (int q = 0; q < 16; ++q) {
            int i = isg * 16 + q;
            const float* c2 = coef2 + (size_t)(i * NOUT + o2) * 8;
            float s = 0.f;
            #pragma unroll
            for (int k = 0; k < 8; ++k) s += Hf[i][k] * c2[k];
            acc += Hf[i][8] * sb2[i * NOUT + o2] + sp2[i * NOUT + o2] * s;
        }
        ((float*)red)[isg * 16 + o2] = acc;
    }
    __syncthreads();
    if (tid < NOUT) {
        float a = 0.f;
        #pragma unroll
        for (int g = 0; g < 8; ++g) a += ((float*)red)[g * 16 + tid];
        out[(size_t)b * NOUT + tid] = a;
    }
}

extern "C" void kernel_launch(void* const* d_in, const int* in_sizes, int n_in,
                              void* d_out, int out_size, void* d_ws, size_t ws_size,
                              hipStream_t stream) {
    kan_seq<<<NB, 1024, 0, stream>>>(
        (const float*)d_in[0], (const float*)d_in[1], (const float*)d_in[2],
        (const float*)d_in[3], (const float*)d_in[4], (const float*)d_in[5],
        (const float*)d_in[6], (float*)d_out);
}

// Round 7
// 1235.793 us; speedup vs baseline: 1.1433x; 1.1433x over previous
//
#include <hip/hip_runtime.h>
#include <hip/hip_bf16.h>

#define NIN 32
#define NHID 128
#define NOUT 16
#define NIN1 160   // NIN+NHID
#define SEQT 512
#define NB 256

#if defined(__has_builtin)
#if __has_builtin(__builtin_amdgcn_fdot2_f32_bf16)
#define HAVE_DOT2BF 1
#endif
#endif
#ifndef HAVE_DOT2BF
#define HAVE_DOT2BF 0
#endif

__device__ __forceinline__ unsigned int f2bfbits(float f) {
    unsigned int u = __float_as_uint(f);
    return (u + 0x7fffu + ((u >> 16) & 1u)) >> 16;
}
__device__ __forceinline__ unsigned int packbf(float lo, float hi) {
    return f2bfbits(lo) | (f2bfbits(hi) << 16);
}

#if HAVE_DOT2BF
typedef __bf16 bf16x2 __attribute__((ext_vector_type(2)));
__device__ __forceinline__ float dot2w(unsigned int a, unsigned int b, float c) {
    return __builtin_amdgcn_fdot2_f32_bf16(__builtin_bit_cast(bf16x2, a),
                                           __builtin_bit_cast(bf16x2, b), c, false);
}
#else
__device__ __forceinline__ float dot2w(unsigned int a, unsigned int b, float c) {
    float alo = __uint_as_float(a << 16), ahi = __uint_as_float(a & 0xffff0000u);
    float blo = __uint_as_float(b << 16), bhi = __uint_as_float(b & 0xffff0000u);
    return __builtin_fmaf(ahi, bhi, __builtin_fmaf(alo, blo, c));
}
#endif

// Knots: t_m = -8.8 + 1.6*m (G=5, K=3, range [-4,4]); verified rounds 3-6 PASS.
__device__ __forceinline__ void spline_feat(float c, float* out4, int* jst) {
    const float t0 = -8.8f, hh = 1.6f;
    int m0 = (int)floorf((c - t0) / hh);
    bool valid = (m0 >= 0) && (m0 <= 10);
    float v0 = 1.f, v1 = 0.f, v2 = 0.f, v3 = 0.f;
    #pragma unroll
    for (int d = 1; d <= 3; ++d) {
        float inv = 1.f / (d * hh);
        float nv[4];
        float pv[4] = {v0, v1, v2, v3};
        #pragma unroll
        for (int r = 3; r >= 0; --r) {
            if (r > d) { nv[r] = 0.f; continue; }
            int m = m0 - d + r;
            float tm = t0 + hh * (float)m;
            float left  = (r >= 1) ? pv[r-1] : 0.f;
            float right = (r <= d-1) ? pv[r] : 0.f;
            nv[r] = ((c - tm) * left + (tm + hh * (float)(d+1) - c) * right) * inv;
        }
        v0 = nv[0]; v1 = nv[1]; v2 = nv[2]; v3 = nv[3];
    }
    float v[4] = {v0, v1, v2, v3};
    int jb = m0 - 3;
    int js = jb < 0 ? 0 : (jb > 4 ? 4 : jb);
    int sh = js - jb;
    #pragma unroll
    for (int r = 0; r < 4; ++r) {
        int rs = r + sh;
        out4[r] = (valid && rs >= 0 && rs <= 3) ? v[rs] : 0.f;
    }
    *jst = js;
}

__device__ __forceinline__ float fsilu(float c) {
    return c * __builtin_amdgcn_rcpf(1.f + __expf(-c));
}

__device__ __forceinline__ unsigned int RL(unsigned int v, int lane) {
    return (unsigned int)__builtin_amdgcn_readlane((int)v, lane);
}

// Compute the 8-padded basis + silu for value c; pack basis into uint4.
__device__ __forceinline__ void feat_record(float c, uint4* pk, float* sil) {
    *sil = fsilu(c);
    float b4[4]; int js;
    spline_feat(c, b4, &js);
    float e[8];
    #pragma unroll
    for (int k = 0; k < 8; ++k) {
        int d = k - js;
        e[k] = (d >= 0 && d < 4) ? b4[d] : 0.f;
    }
    pk->x = packbf(e[0], e[1]); pk->y = packbf(e[2], e[3]);
    pk->z = packbf(e[4], e[5]); pk->w = packbf(e[6], e[7]);
}

// ===================== BIG kernel: >80 KB LDS -> 1 block/CU -> 256-VGPR budget ====
// seg s (0..3) covers i in [s*40, s*40+40): first 32 in registers, last 8 in LDS.
__global__ void __launch_bounds__(512, 2)
kan_big(const float* __restrict__ x,
        const float* __restrict__ coef1,
        const float* __restrict__ sb1,
        const float* __restrict__ sp1,
        const float* __restrict__ coef2,
        const float* __restrict__ sb2,
        const float* __restrict__ sp2,
        float* __restrict__ out)
{
    __shared__ __align__(16) uint4 WcL[32 * 128];        // 65536 B (LDS-i coef, bf16x8)
    __shared__ float WsbL[32 * 128];                     // 16384 B (LDS-i sb, f32)
    __shared__ __align__(16) unsigned int Frec[160 * 8]; // 5120 B, 32-B records
    __shared__ float red[4][NHID];                       // 2048 B
    __shared__ float Hf[NHID][9];                        // 4608 B
    // total 93,696 B -> only 1 block/CU fits (160 KB LDS); compiler occupancy
    // heuristic then targets 2 waves/EU -> VGPR budget 256.

    const int tid  = threadIdx.x;
    const int b    = blockIdx.x;
    const int o    = tid & 127;
    const int seg  = tid >> 7;      // 0..3
    const int lane = tid & 63;

    // ---- LDS weights: iL in [0,32): i = (iL>>3)*40 + 32 + (iL&7) ----
    for (int p = tid; p < 32 * 128; p += 512) {
        int iL = p >> 7, oo = p & 127;
        int i = (iL >> 3) * 40 + 32 + (iL & 7);
        const float4* cp = (const float4*)(coef1 + (size_t)(i * NHID + oo) * 8);
        float sp = sp1[i * NHID + oo];
        float4 a = cp[0], c = cp[1];
        WcL[p] = make_uint4(packbf(sp * a.x, sp * a.y), packbf(sp * a.z, sp * a.w),
                            packbf(sp * c.x, sp * c.y), packbf(sp * c.z, sp * c.w));
        WsbL[p] = sb1[i * NHID + oo];
    }
    // ---- register weights: r in [0,32): i = seg*40 + r ----
    uint4 wc[32];
    float sbv[32];
    #pragma unroll
    for (int r = 0; r < 32; ++r) {
        int i = seg * 40 + r;
        const float4* cp = (const float4*)(coef1 + (size_t)(i * NHID + o) * 8);
        float sp = sp1[i * NHID + o];
        float4 a = cp[0], c = cp[1];
        wc[r] = make_uint4(packbf(sp * a.x, sp * a.y), packbf(sp * a.z, sp * a.w),
                           packbf(sp * c.x, sp * c.y), packbf(sp * c.z, sp * c.w));
        sbv[r] = sb1[i * NHID + o];
    }

    ((float*)red)[tid] = 0.f;   // h0 = 0 (red is exactly 512 floats)
    float xv = (tid < NIN) ? x[(size_t)b * SEQT * NIN + tid] : 0.f;
    __syncthreads();

    for (int t = 0; t < SEQT; ++t) {
        // ---- phase 1: features for all 160 inputs -> 32-B records ----
        if (tid < NIN1) {
            float c;
            if (tid < NIN) c = xv;
            else {
                int hi = tid - NIN;
                c = (red[0][hi] + red[1][hi]) + (red[2][hi] + red[3][hi]);
            }
            uint4 pk; float sil;
            feat_record(c, &pk, &sil);
            unsigned int* R = &Frec[tid * 8];
            *(uint4*)R = pk;
            R[4] = __float_as_uint(sil);
        }
        if (tid < NIN) {
            int tn = (t + 1 < SEQT) ? (t + 1) : t;
            xv = x[((size_t)b * SEQT + tn) * NIN + tid];
        }
        __syncthreads();

        // ---- phase 2: wide-fetch features (2 LDS insts/wave), readlane->SGPR,
        //      dot2 against register/LDS weights ----
        const int segbase = seg * 40 * 8;   // uints
        uint4 vA = *(const uint4*)&Frec[segbase + lane * 4];        // records 0..31
        uint4 vB = make_uint4(0, 0, 0, 0);
        if (lane < 16) vB = *(const uint4*)&Frec[segbase + 256 + lane * 4]; // 32..39

        float ac0 = 0.f, ac1 = 0.f, ac2 = 0.f, ac3 = 0.f;
        #pragma unroll
        for (int r = 0; r < 32; ++r) {
            unsigned int f0 = RL(vA.x, 2 * r), f1 = RL(vA.y, 2 * r);
            unsigned int f2 = RL(vA.z, 2 * r), f3 = RL(vA.w, 2 * r);
            float sl = __uint_as_float(RL(vA.x, 2 * r + 1));
            ac0 = dot2w(f0, wc[r].x, ac0);
            ac1 = dot2w(f1, wc[r].y, ac1);
            ac2 = dot2w(f2, wc[r].z, ac2);
            ac3 = dot2w(f3, wc[r].w, ac3);
            ac0 = __builtin_fmaf(sl, sbv[r], ac0);
        }
        #pragma unroll
        for (int q = 0; q < 8; ++q) {
            int iL = seg * 8 + q;
            uint4 wv = WcL[(iL << 7) + o];
            float sbw = WsbL[(iL << 7) + o];
            unsigned int f0 = RL(vB.x, 2 * q), f1 = RL(vB.y, 2 * q);
            unsigned int f2 = RL(vB.z, 2 * q), f3 = RL(vB.w, 2 * q);
            float sl = __uint_as_float(RL(vB.x, 2 * q + 1));
            ac0 = dot2w(f0, wv.x, ac0);
            ac1 = dot2w(f1, wv.y, ac1);
            ac2 = dot2w(f2, wv.z, ac2);
            ac3 = dot2w(f3, wv.w, ac3);
            ac1 = __builtin_fmaf(sl, sbw, ac1);
        }
        red[seg][o] = (ac0 + ac1) + (ac2 + ac3);
        __syncthreads();
    }

    // ---- layer 2 on final h only (fp32; verified rounds 3-6) ----
    if (tid < NHID) {
        float c = (red[0][tid] + red[1][tid]) + (red[2][tid] + red[3][tid]);
        float sil = fsilu(c);
        float b4[4]; int js;
        spline_feat(c, b4, &js);
        #pragma unroll
        for (int k = 0; k < 8; ++k) {
            int d = k - js;
            Hf[tid][k] = (d >= 0 && d < 4) ? b4[d] : 0.f;
        }
        Hf[tid][8] = sil;
    }
    __syncthreads();
    if (tid < 128) {
        int o2 = tid & 15, isg = tid >> 4;
        float acc = 0.f;
        for (int q = 0; q < 16; ++q) {
            int i = isg * 16 + q;
            const float* c2 = coef2 + (size_t)(i * NOUT + o2) * 8;
            float s = 0.f;
            #pragma unroll
            for (int k = 0; k < 8; ++k) s += Hf[i][k] * c2[k];
            acc += Hf[i][8] * sb2[i * NOUT + o2] + sp2[i * NOUT + o2] * s;
        }
        ((float*)red)[isg * 16 + o2] = acc;
    }
    __syncthreads();
    if (tid < NOUT) {
        float a = 0.f;
        #pragma unroll
        for (int g = 0; g < 8; ++g) a += ((float*)red)[g * 16 + tid];
        out[(size_t)b * NOUT + tid] = a;
    }
}

// ===================== SAFE kernel: round-5 verbatim (known 1063 us, passed) =====
#define SEGI 40
#define R20(X) X(0) X(1) X(2) X(3) X(4) X(5) X(6) X(7) X(8) X(9) \
               X(10) X(11) X(12) X(13) X(14) X(15) X(16) X(17) X(18) X(19)

__global__ void __launch_bounds__(512)
kan_safe(const float* __restrict__ x,
         const float* __restrict__ coef1,
         const float* __restrict__ sb1,
         const float* __restrict__ sp1,
         const float* __restrict__ coef2,
         const float* __restrict__ sb2,
         const float* __restrict__ sp2,
         float* __restrict__ out)
{
    __shared__ __align__(16) unsigned int Fb[NIN1][4];
    __shared__ float Fsil[NIN1];
    __shared__ float red[4][NHID];
    __shared__ float Hf[NHID][9];

    const int tid  = threadIdx.x;
    const int b    = blockIdx.x;
    const int o    = tid & 127;
    const int seg  = tid >> 7;
    const int i0   = seg * SEGI;
    const int lane = tid & 63;

#define DECLP(p) uint4 wA##p, wB##p; unsigned int sbp##p;
    R20(DECLP)
#undef DECLP
#define INITP(p) { \
    const int iA = i0 + 2 * (p), iB = i0 + 2 * (p) + 1; \
    const float4* ca = (const float4*)(coef1 + (size_t)(iA * NHID + o) * 8); \
    const float4* cb = (const float4*)(coef1 + (size_t)(iB * NHID + o) * 8); \
    float spA = sp1[iA * NHID + o], spB = sp1[iB * NHID + o]; \
    float4 a0 = ca[0], a1 = ca[1], b0v = cb[0], b1v = cb[1]; \
    wA##p = make_uint4(packbf(spA * a0.x, spA * a0.y), packbf(spA * a0.z, spA * a0.w), \
                       packbf(spA * a1.x, spA * a1.y), packbf(spA * a1.z, spA * a1.w)); \
    wB##p = make_uint4(packbf(spB * b0v.x, spB * b0v.y), packbf(spB * b0v.z, spB * b0v.w), \
                       packbf(spB * b1v.x, spB * b1v.y), packbf(spB * b1v.z, spB * b1v.w)); \
    sbp##p = packbf(sb1[iA * NHID + o], sb1[iB * NHID + o]); }
    R20(INITP)
#undef INITP

    ((float*)red)[tid] = 0.f;
    float xv = (tid < NIN) ? x[(size_t)b * SEQT * NIN + tid] : 0.f;
    __syncthreads();

    for (int t = 0; t < SEQT; ++t) {
        if (tid < NIN1) {
            float c;
            if (tid < NIN) c = xv;
            else {
                int hi = tid - NIN;
                c = (red[0][hi] + red[1][hi]) + (red[2][hi] + red[3][hi]);
            }
            uint4 pk; float sil;
            feat_record(c, &pk, &sil);
            *(uint4*)&Fb[tid][0] = pk;
            Fsil[tid] = sil;
        }
        if (tid < NIN) {
            int tn = (t + 1 < SEQT) ? (t + 1) : t;
            xv = x[((size_t)b * SEQT + tn) * NIN + tid];
        }
        __syncthreads();

        float vsil = Fsil[i0 + (lane < SEGI ? lane : 0)];
        float ac0 = 0.f, ac1 = 0.f, ac2 = 0.f, ac3 = 0.f;
#define DOTP(p) { \
        float sb_lo = __uint_as_float(sbp##p << 16); \
        float sb_hi = __uint_as_float(sbp##p & 0xffff0000u); \
        float slA = __int_as_float(__builtin_amdgcn_readlane(__float_as_int(vsil), 2 * (p))); \
        float slB = __int_as_float(__builtin_amdgcn_readlane(__float_as_int(vsil), 2 * (p) + 1)); \
        uint4 bA = *(const uint4*)&Fb[i0 + 2 * (p)][0]; \
        uint4 bB = *(const uint4*)&Fb[i0 + 2 * (p) + 1][0]; \
        ac0 = __builtin_fmaf(slA, sb_lo, ac0); \
        ac0 = dot2w(bA.x, wA##p.x, ac0); ac1 = dot2w(bA.y, wA##p.y, ac1); \
        ac2 = dot2w(bA.z, wA##p.z, ac2); ac3 = dot2w(bA.w, wA##p.w, ac3); \
        ac1 = __builtin_fmaf(slB, sb_hi, ac1); \
        ac0 = dot2w(bB.x, wB##p.x, ac0); ac1 = dot2w(bB.y, wB##p.y, ac1); \
        ac2 = dot2w(bB.z, wB##p.z, ac2); ac3 = dot2w(bB.w, wB##p.w, ac3); }
        R20(DOTP)
#undef DOTP
        red[seg][o] = (ac0 + ac1) + (ac2 + ac3);
        __syncthreads();
    }

    if (tid < NHID) {
        float c = (red[0][tid] + red[1][tid]) + (red[2][tid] + red[3][tid]);
        float sil = fsilu(c);
        float b4[4]; int js;
        spline_feat(c, b4, &js);
        #pragma unroll
        for (int k = 0; k < 8; ++k) {
            int d = k - js;
            Hf[tid][k] = (d >= 0 && d < 4) ? b4[d] : 0.f;
        }
        Hf[tid][8] = sil;
    }
    __syncthreads();
    if (tid < 128) {
        int o2 = tid & 15, isg = tid >> 4;
        float acc = 0.f;
        for (int q = 0; q < 16; ++q) {
            int i = isg * 16 + q;
            const float* c2 = coef2 + (size_t)(i * NOUT + o2) * 8;
            float s = 0.f;
            #pragma unroll
            for (int k = 0; k < 8; ++k) s += Hf[i][k] * c2[k];
            acc += Hf[i][8] * sb2[i * NOUT + o2] + sp2[i * NOUT + o2] * s;
        }
        ((float*)red)[isg * 16 + o2] = acc;
    }
    __syncthreads();
    if (tid < NOUT) {
        float a = 0.f;
        #pragma unroll
        for (int g = 0; g < 8; ++g) a += ((float*)red)[g * 16 + tid];
        out[(size_t)b * NOUT + tid] = a;
    }
}

extern "C" void kernel_launch(void* const* d_in, const int* in_sizes, int n_in,
                              void* d_out, int out_size, void* d_ws, size_t ws_size,
                              hipStream_t stream) {
    const float* x     = (const float*)d_in[0];
    const float* coef1 = (const float*)d_in[1];
    const float* sb1   = (const float*)d_in[2];
    const float* sp1   = (const float*)d_in[3];
    const float* coef2 = (const float*)d_in[4];
    const float* sb2   = (const float*)d_in[5];
    const float* sp2   = (const float*)d_in[6];
    float* outp = (float*)d_out;

    // Pick kernel by whether the compiler actually granted the big register
    // budget (capture-safe host-side metadata query; same result every call).
    hipFuncAttributes attr;
    hipError_t e = hipFuncGetAttributes(&attr, reinterpret_cast<const void*>(kan_big));
    bool use_big = (e == hipSuccess) && (attr.numRegs >= 160);

    if (use_big)
        kan_big<<<NB, 512, 0, stream>>>(x, coef1, sb1, sp1, coef2, sb2, sp2, outp);
    else
        kan_safe<<<NB, 512, 0, stream>>>(x, coef1, sb1, sp1, coef2, sb2, sp2, outp);
}